// Round 1
// baseline (105.447 us; speedup 1.0000x reference)
//
#include <hip/hip_runtime.h>
#include <math.h>

#define L_LEN 720
#define PAD 4
#define NT 256

__global__ __launch_bounds__(NT) void trend_kernel(
    const float* __restrict__ x,
    const float* __restrict__ cw0, const float* __restrict__ cb0,
    const float* __restrict__ cw1, const float* __restrict__ cb1,
    const float* __restrict__ cw2, const float* __restrict__ cb2,
    const float* __restrict__ cw3, const float* __restrict__ cb3,
    const float* __restrict__ W1, const float* __restrict__ b1,
    const float* __restrict__ W2, const float* __restrict__ b2,
    float* __restrict__ out)
{
    __shared__ float xs[L_LEN + 2 * PAD];
    __shared__ float fbuf[4][L_LEN];
    __shared__ float redM[4][4];
    __shared__ float redS[4][4];
    __shared__ float redT[4][4];
    __shared__ float ent_sh[4];
    __shared__ float wts_sh[4];

    const int row = blockIdx.x;
    const int tid = threadIdx.x;
    const float* __restrict__ xr = x + (size_t)row * L_LEN;

    // zero the pads
    if (tid < 2 * PAD) {
        xs[(tid < PAD) ? tid : (L_LEN + tid)] = 0.0f;
    }
    for (int j = tid; j < L_LEN; j += NT) xs[PAD + j] = xr[j];

    // conv weights -> registers (uniform addresses -> scalar loads)
    const float* cws[4] = {cw0, cw1, cw2, cw3};
    const float* cbs[4] = {cb0, cb1, cb2, cb3};
    float w[4][9];
    float bias[4];
#pragma unroll
    for (int s = 0; s < 4; ++s) {
        const int k = 3 + 2 * s;
        bias[s] = cbs[s][0];
#pragma unroll
        for (int t = 0; t < 9; ++t) w[s][t] = (t < k) ? cws[s][t] : 0.0f;
    }
    __syncthreads();

    // pass 1: convs -> fbuf, track per-scale max
    float mx[4] = {-INFINITY, -INFINITY, -INFINITY, -INFINITY};
    for (int j = tid; j < L_LEN; j += NT) {
#pragma unroll
        for (int s = 0; s < 4; ++s) {
            const int k = 3 + 2 * s;
            const int h = 1 + s;               // k/2
            float acc = bias[s];
#pragma unroll
            for (int t = 0; t < k; ++t)
                acc = fmaf(w[s][t], xs[PAD + j - h + t], acc);
            fbuf[s][j] = acc;
            mx[s] = fmaxf(mx[s], acc);
        }
    }

    const int lane = tid & 63;
    const int wid  = tid >> 6;

    // wave reduce max, then cross-wave via LDS
#pragma unroll
    for (int s = 0; s < 4; ++s) {
#pragma unroll
        for (int off = 32; off > 0; off >>= 1)
            mx[s] = fmaxf(mx[s], __shfl_xor(mx[s], off));
    }
    if (lane == 0) {
#pragma unroll
        for (int s = 0; s < 4; ++s) redM[s][wid] = mx[s];
    }
    __syncthreads();
#pragma unroll
    for (int s = 0; s < 4; ++s)
        mx[s] = fmaxf(fmaxf(redM[s][0], redM[s][1]),
                      fmaxf(redM[s][2], redM[s][3]));

    // pass 2: S = sum e^g, T = sum g e^g  (g = f - max)
    float Ss[4] = {0.f, 0.f, 0.f, 0.f};
    float Ts[4] = {0.f, 0.f, 0.f, 0.f};
    for (int j = tid; j < L_LEN; j += NT) {
#pragma unroll
        for (int s = 0; s < 4; ++s) {
            float g = fbuf[s][j] - mx[s];
            float e = __expf(g);
            Ss[s] += e;
            Ts[s] = fmaf(g, e, Ts[s]);
        }
    }
#pragma unroll
    for (int s = 0; s < 4; ++s) {
#pragma unroll
        for (int off = 32; off > 0; off >>= 1) {
            Ss[s] += __shfl_xor(Ss[s], off);
            Ts[s] += __shfl_xor(Ts[s], off);
        }
    }
    if (lane == 0) {
#pragma unroll
        for (int s = 0; s < 4; ++s) { redS[s][wid] = Ss[s]; redT[s][wid] = Ts[s]; }
    }
    __syncthreads();

    if (tid < 4) {
        const int s = tid;
        float S = redS[s][0] + redS[s][1] + redS[s][2] + redS[s][3];
        float T = redT[s][0] + redT[s][1] + redT[s][2] + redT[s][3];
        // entropy = -sum p log p = log S - T/S  (the +1e-8 in ref is negligible)
        ent_sh[s] = __logf(S) - T / S;
    }
    __syncthreads();

    // MLP on lanes 0..31 of wave 0: h = relu(ent @ W1 + b1); logits = h @ W2 + b2
    if (tid < 32) {
        const float e0 = ent_sh[0], e1 = ent_sh[1], e2 = ent_sh[2], e3 = ent_sh[3];
        float h = b1[tid];
        h = fmaf(e0, W1[tid],      h);
        h = fmaf(e1, W1[32 + tid], h);
        h = fmaf(e2, W1[64 + tid], h);
        h = fmaf(e3, W1[96 + tid], h);
        h = fmaxf(h, 0.0f);
        float lg[4];
#pragma unroll
        for (int c = 0; c < 4; ++c) {
            float v = h * W2[tid * 4 + c];
#pragma unroll
            for (int off = 16; off > 0; off >>= 1)
                v += __shfl_xor(v, off);
            lg[c] = v + b2[c];
        }
        if (tid == 0) {
            float m = fmaxf(fmaxf(lg[0], lg[1]), fmaxf(lg[2], lg[3]));
            float e0w = __expf(lg[0] - m), e1w = __expf(lg[1] - m);
            float e2w = __expf(lg[2] - m), e3w = __expf(lg[3] - m);
            float inv = 1.0f / (e0w + e1w + e2w + e3w);
            wts_sh[0] = e0w * inv; wts_sh[1] = e1w * inv;
            wts_sh[2] = e2w * inv; wts_sh[3] = e3w * inv;
        }
    }
    __syncthreads();

    const float w0 = wts_sh[0], w1 = wts_sh[1], w2 = wts_sh[2], w3 = wts_sh[3];
    float* __restrict__ orow = out + (size_t)row * L_LEN;
    for (int j = tid; j < L_LEN; j += NT) {
        float v = w0 * fbuf[0][j];
        v = fmaf(w1, fbuf[1][j], v);
        v = fmaf(w2, fbuf[2][j], v);
        v = fmaf(w3, fbuf[3][j], v);
        orow[j] = v;
    }
}

extern "C" void kernel_launch(void* const* d_in, const int* in_sizes, int n_in,
                              void* d_out, int out_size, void* d_ws, size_t ws_size,
                              hipStream_t stream) {
    const float* xp  = (const float*)d_in[0];
    const float* cw0 = (const float*)d_in[1];
    const float* cb0 = (const float*)d_in[2];
    const float* cw1 = (const float*)d_in[3];
    const float* cb1 = (const float*)d_in[4];
    const float* cw2 = (const float*)d_in[5];
    const float* cb2 = (const float*)d_in[6];
    const float* cw3 = (const float*)d_in[7];
    const float* cb3 = (const float*)d_in[8];
    const float* W1  = (const float*)d_in[9];
    const float* b1  = (const float*)d_in[10];
    const float* W2  = (const float*)d_in[11];
    const float* b2  = (const float*)d_in[12];
    float* outp = (float*)d_out;

    const int rows = 64 * 321;  // B*N
    trend_kernel<<<rows, NT, 0, stream>>>(xp, cw0, cb0, cw1, cb1, cw2, cb2,
                                          cw3, cb3, W1, b1, W2, b2, outp);
}

// Round 2
// 40.688 us; speedup vs baseline: 2.5916x; 2.5916x over previous
//
#include <hip/hip_runtime.h>
#include <math.h>

#define NT 256
#define L_LEN 720
#define NROWS (64 * 321)   // 20544, divisible by 4

__global__ __launch_bounds__(NT) void trend_kernel(
    const float* __restrict__ x,
    const float* __restrict__ cw0, const float* __restrict__ cb0,
    const float* __restrict__ cw1, const float* __restrict__ cb1,
    const float* __restrict__ cw2, const float* __restrict__ cb2,
    const float* __restrict__ cw3, const float* __restrict__ cb3,
    const float* __restrict__ W1, const float* __restrict__ b1,
    const float* __restrict__ W2, const float* __restrict__ b2,
    float* __restrict__ out)
{
    // one wave per row; 4 rows per block; per-wave private row buffer
    __shared__ __align__(16) float xs[4][744];   // 4 pad + 720 + 4 pad (+ slack)

    const int lane = threadIdx.x & 63;
    const int wid  = threadIdx.x >> 6;
    const int row  = blockIdx.x * 4 + wid;

    const float* __restrict__ xr = x + (size_t)row * L_LEN;
    float* xsw = xs[wid];

    // stage row into LDS (float4 coalesced), zero the halo pads
    if (lane < 4) { xsw[lane] = 0.0f; xsw[724 + lane] = 0.0f; }
    {
        const float4* __restrict__ src = (const float4*)xr;   // 180 float4
        float4* dst = (float4*)(xsw + 4);
        dst[lane]      = src[lane];
        dst[lane + 64] = src[lane + 64];
        if (lane < 52) dst[lane + 128] = src[lane + 128];
    }

    // conv weights -> uniform (scalar) regs
    const float* cws[4] = {cw0, cw1, cw2, cw3};
    const float* cbs[4] = {cb0, cb1, cb2, cb3};
    float w[4][9], bias[4];
#pragma unroll
    for (int s = 0; s < 4; ++s) {
        const int k = 3 + 2 * s;
        bias[s] = cbs[s][0];
#pragma unroll
        for (int t = 0; t < 9; ++t) w[s][t] = (t < k) ? cws[s][t] : 0.0f;
    }
    __syncthreads();   // also orders LDS writes vs cross-lane reads

    // lane t owns elements 12t .. 12t+11 ; lanes 60..63 idle (60*12 == 720)
    const bool active = lane < 60;
    float f[4][12];
    float mx[4] = {-1e30f, -1e30f, -1e30f, -1e30f};

    if (active) {
        float xw[20];   // x[12t-4 .. 12t+15], pad-shifted: dwords 12t .. 12t+19
#pragma unroll
        for (int q = 0; q < 5; ++q) {
            float4 v = *(const float4*)(xsw + 12 * lane + 4 * q);
            xw[4 * q + 0] = v.x; xw[4 * q + 1] = v.y;
            xw[4 * q + 2] = v.z; xw[4 * q + 3] = v.w;
        }
#pragma unroll
        for (int s = 0; s < 4; ++s) {
            const int k = 3 + 2 * s;
            const int off = 3 - s;          // (4 - k/2)
#pragma unroll
            for (int e = 0; e < 12; ++e) {
                float acc = bias[s];
#pragma unroll
                for (int u = 0; u < k; ++u)
                    acc = fmaf(w[s][u], xw[e + off + u], acc);
                f[s][e] = acc;
                mx[s] = fmaxf(mx[s], acc);
            }
        }
    } else {
#pragma unroll
        for (int s = 0; s < 4; ++s)
#pragma unroll
            for (int e = 0; e < 12; ++e) f[s][e] = -1e30f;
    }

    // wave-wide max per scale
#pragma unroll
    for (int s = 0; s < 4; ++s) {
#pragma unroll
        for (int off = 32; off; off >>= 1)
            mx[s] = fmaxf(mx[s], __shfl_xor(mx[s], off));
    }

    // S = sum e^g, T = sum g*e^g  (g = f - max); entropy = log S - T/S
    float S[4] = {0.f, 0.f, 0.f, 0.f};
    float T[4] = {0.f, 0.f, 0.f, 0.f};
#pragma unroll
    for (int s = 0; s < 4; ++s) {
#pragma unroll
        for (int e = 0; e < 12; ++e) {
            float g = f[s][e] - mx[s];      // inactive: ~ -1e30 -> exp = 0, g*0 = -0
            float ev = __expf(g);
            S[s] += ev;
            T[s] = fmaf(g, ev, T[s]);
        }
    }
#pragma unroll
    for (int s = 0; s < 4; ++s) {
#pragma unroll
        for (int off = 32; off; off >>= 1) {
            S[s] += __shfl_xor(S[s], off);
            T[s] += __shfl_xor(T[s], off);
        }
    }
    float ent[4];
#pragma unroll
    for (int s = 0; s < 4; ++s) ent[s] = __logf(S[s]) - T[s] / S[s];

    // MLP: h = relu(ent @ W1 + b1) (32 units, one per lane in each 32-half),
    // logits = h @ W2 + b2 via 32-lane reduction; softmax -> mixing weights
    const int hidx = lane & 31;
    float h = b1[hidx];
#pragma unroll
    for (int s = 0; s < 4; ++s) h = fmaf(ent[s], W1[s * 32 + hidx], h);
    h = fmaxf(h, 0.0f);

    const float4 w2v = ((const float4*)W2)[hidx];   // W2 row for this hidden unit
    float lg[4] = {h * w2v.x, h * w2v.y, h * w2v.z, h * w2v.w};
#pragma unroll
    for (int c = 0; c < 4; ++c) {
#pragma unroll
        for (int off = 16; off; off >>= 1)
            lg[c] += __shfl_xor(lg[c], off);
    }
    lg[0] += b2[0]; lg[1] += b2[1]; lg[2] += b2[2]; lg[3] += b2[3];

    float m = fmaxf(fmaxf(lg[0], lg[1]), fmaxf(lg[2], lg[3]));
    float e0 = __expf(lg[0] - m), e1 = __expf(lg[1] - m);
    float e2 = __expf(lg[2] - m), e3 = __expf(lg[3] - m);
    float inv = 1.0f / (e0 + e1 + e2 + e3);
    const float w0 = e0 * inv, w1 = e1 * inv, w2 = e2 * inv, w3 = e3 * inv;

    // weighted sum from registers, float4 stores
    if (active) {
        float* __restrict__ orow = out + (size_t)row * L_LEN + 12 * lane;
#pragma unroll
        for (int q = 0; q < 3; ++q) {
            float4 v;
#pragma unroll
            for (int c = 0; c < 4; ++c) {
                const int e = 4 * q + c;
                float val = w0 * f[0][e];
                val = fmaf(w1, f[1][e], val);
                val = fmaf(w2, f[2][e], val);
                val = fmaf(w3, f[3][e], val);
                ((float*)&v)[c] = val;
            }
            *(float4*)(orow + 4 * q) = v;
        }
    }
}

extern "C" void kernel_launch(void* const* d_in, const int* in_sizes, int n_in,
                              void* d_out, int out_size, void* d_ws, size_t ws_size,
                              hipStream_t stream) {
    const float* xp  = (const float*)d_in[0];
    const float* cw0 = (const float*)d_in[1];
    const float* cb0 = (const float*)d_in[2];
    const float* cw1 = (const float*)d_in[3];
    const float* cb1 = (const float*)d_in[4];
    const float* cw2 = (const float*)d_in[5];
    const float* cb2 = (const float*)d_in[6];
    const float* cw3 = (const float*)d_in[7];
    const float* cb3 = (const float*)d_in[8];
    const float* W1  = (const float*)d_in[9];
    const float* b1  = (const float*)d_in[10];
    const float* W2  = (const float*)d_in[11];
    const float* b2  = (const float*)d_in[12];
    float* outp = (float*)d_out;

    trend_kernel<<<NROWS / 4, NT, 0, stream>>>(xp, cw0, cb0, cw1, cb1, cw2, cb2,
                                               cw3, cb3, W1, b1, W2, b2, outp);
}

// Round 3
// 40.626 us; speedup vs baseline: 2.5956x; 1.0015x over previous
//
#include <hip/hip_runtime.h>
#include <math.h>

#define NT 256
#define L_LEN 720
#define NROWS (64 * 321)   // 20544, divisible by 4

__global__ __launch_bounds__(NT, 4) void trend_kernel(
    const float* __restrict__ x,
    const float* __restrict__ cw0, const float* __restrict__ cb0,
    const float* __restrict__ cw1, const float* __restrict__ cb1,
    const float* __restrict__ cw2, const float* __restrict__ cb2,
    const float* __restrict__ cw3, const float* __restrict__ cb3,
    const float* __restrict__ W1, const float* __restrict__ b1,
    const float* __restrict__ W2, const float* __restrict__ b2,
    float* __restrict__ out)
{
    // one wave per row; 4 rows per block; no LDS, no barriers
    const int lane = threadIdx.x & 63;
    const int wid  = threadIdx.x >> 6;
    const int row  = blockIdx.x * 4 + wid;

    const float* __restrict__ xr = x + (size_t)row * L_LEN;

    // conv weights -> uniform (scalar) regs
    const float* cws[4] = {cw0, cw1, cw2, cw3};
    const float* cbs[4] = {cb0, cb1, cb2, cb3};
    float w[4][9], bias[4];
#pragma unroll
    for (int s = 0; s < 4; ++s) {
        const int k = 3 + 2 * s;
        bias[s] = cbs[s][0];
#pragma unroll
        for (int t = 0; t < 9; ++t) w[s][t] = (t < k) ? cws[s][t] : 0.0f;
    }

    // lane t owns elements 12t .. 12t+11 ; lanes 60..63 idle (60*12 == 720)
    const bool active = lane < 60;
    float f[4][12];
    float mx[4] = {-1e30f, -1e30f, -1e30f, -1e30f};

    if (active) {
        // window: elements e0 .. e0+19, e0 = 12*lane - 4 (halo 4 each side)
        const int e0 = 12 * lane - 4;
        float xw[20];
#pragma unroll
        for (int q = 0; q < 5; ++q) {
            int e = e0 + 4 * q;
            e = (e < 0) ? 0 : ((e > L_LEN - 4) ? (L_LEN - 4) : e);   // stays 16B-aligned
            float4 v = *(const float4*)(xr + e);
            xw[4 * q + 0] = v.x; xw[4 * q + 1] = v.y;
            xw[4 * q + 2] = v.z; xw[4 * q + 3] = v.w;
        }
        if (lane == 0)  { xw[0] = 0.f; xw[1] = 0.f; xw[2] = 0.f; xw[3] = 0.f; }
        if (lane == 59) { xw[16] = 0.f; xw[17] = 0.f; xw[18] = 0.f; xw[19] = 0.f; }

#pragma unroll
        for (int s = 0; s < 4; ++s) {
            const int k = 3 + 2 * s;
            const int off = 3 - s;          // 4 - k/2
#pragma unroll
            for (int e = 0; e < 12; ++e) {
                float acc = bias[s];
#pragma unroll
                for (int u = 0; u < k; ++u)
                    acc = fmaf(w[s][u], xw[e + off + u], acc);
                f[s][e] = acc;
                mx[s] = fmaxf(mx[s], acc);
            }
        }
    } else {
#pragma unroll
        for (int s = 0; s < 4; ++s)
#pragma unroll
            for (int e = 0; e < 12; ++e) f[s][e] = -1e30f;
    }

    // wave-wide max per scale
#pragma unroll
    for (int s = 0; s < 4; ++s) {
#pragma unroll
        for (int off = 32; off; off >>= 1)
            mx[s] = fmaxf(mx[s], __shfl_xor(mx[s], off));
    }

    // S = sum e^g, T = sum g*e^g  (g = f - max); entropy = log S - T/S
    float S[4] = {0.f, 0.f, 0.f, 0.f};
    float T[4] = {0.f, 0.f, 0.f, 0.f};
#pragma unroll
    for (int s = 0; s < 4; ++s) {
#pragma unroll
        for (int e = 0; e < 12; ++e) {
            float g = f[s][e] - mx[s];      // inactive: finite negative -> exp = 0
            float ev = __expf(g);
            S[s] += ev;
            T[s] = fmaf(g, ev, T[s]);
        }
    }
#pragma unroll
    for (int s = 0; s < 4; ++s) {
#pragma unroll
        for (int off = 32; off; off >>= 1) {
            S[s] += __shfl_xor(S[s], off);
            T[s] += __shfl_xor(T[s], off);
        }
    }
    float ent[4];
#pragma unroll
    for (int s = 0; s < 4; ++s) ent[s] = __logf(S[s]) - T[s] / S[s];

    // MLP: h = relu(ent @ W1 + b1), one hidden unit per lane (mod 32);
    // logits = h @ W2 + b2 via 32-lane shuffle reduce; softmax -> weights
    const int hidx = lane & 31;
    float h = b1[hidx];
#pragma unroll
    for (int s = 0; s < 4; ++s) h = fmaf(ent[s], W1[s * 32 + hidx], h);
    h = fmaxf(h, 0.0f);

    const float4 w2v = ((const float4*)W2)[hidx];
    float lg[4] = {h * w2v.x, h * w2v.y, h * w2v.z, h * w2v.w};
#pragma unroll
    for (int c = 0; c < 4; ++c) {
#pragma unroll
        for (int off = 16; off; off >>= 1)
            lg[c] += __shfl_xor(lg[c], off);
    }
    lg[0] += b2[0]; lg[1] += b2[1]; lg[2] += b2[2]; lg[3] += b2[3];

    float m = fmaxf(fmaxf(lg[0], lg[1]), fmaxf(lg[2], lg[3]));
    float e0w = __expf(lg[0] - m), e1w = __expf(lg[1] - m);
    float e2w = __expf(lg[2] - m), e3w = __expf(lg[3] - m);
    float inv = 1.0f / (e0w + e1w + e2w + e3w);
    const float w0 = e0w * inv, w1 = e1w * inv, w2 = e2w * inv, w3 = e3w * inv;

    // weighted sum from registers, float4 stores
    if (active) {
        float* __restrict__ orow = out + (size_t)row * L_LEN + 12 * lane;
#pragma unroll
        for (int q = 0; q < 3; ++q) {
            float4 v;
#pragma unroll
            for (int c = 0; c < 4; ++c) {
                const int e = 4 * q + c;
                float val = w0 * f[0][e];
                val = fmaf(w1, f[1][e], val);
                val = fmaf(w2, f[2][e], val);
                val = fmaf(w3, f[3][e], val);
                ((float*)&v)[c] = val;
            }
            *(float4*)(orow + 4 * q) = v;
        }
    }
}

extern "C" void kernel_launch(void* const* d_in, const int* in_sizes, int n_in,
                              void* d_out, int out_size, void* d_ws, size_t ws_size,
                              hipStream_t stream) {
    const float* xp  = (const float*)d_in[0];
    const float* cw0 = (const float*)d_in[1];
    const float* cb0 = (const float*)d_in[2];
    const float* cw1 = (const float*)d_in[3];
    const float* cb1 = (const float*)d_in[4];
    const float* cw2 = (const float*)d_in[5];
    const float* cb2 = (const float*)d_in[6];
    const float* cw3 = (const float*)d_in[7];
    const float* cb3 = (const float*)d_in[8];
    const float* W1  = (const float*)d_in[9];
    const float* b1  = (const float*)d_in[10];
    const float* W2  = (const float*)d_in[11];
    const float* b2  = (const float*)d_in[12];
    float* outp = (float*)d_out;

    trend_kernel<<<NROWS / 4, NT, 0, stream>>>(xp, cw0, cb0, cw1, cb1, cw2, cb2,
                                               cw3, cb3, W1, b1, W2, b2, outp);
}

// Round 4
// 38.558 us; speedup vs baseline: 2.7347x; 1.0536x over previous
//
#include <hip/hip_runtime.h>
#include <math.h>

#define NT 256
#define L_LEN 720
#define NROWS (64 * 321)   // 20544, divisible by 4

__global__ __launch_bounds__(NT, 4) void trend_kernel(
    const float* __restrict__ x,
    const float* __restrict__ cw0, const float* __restrict__ cb0,
    const float* __restrict__ cw1, const float* __restrict__ cb1,
    const float* __restrict__ cw2, const float* __restrict__ cb2,
    const float* __restrict__ cw3, const float* __restrict__ cb3,
    const float* __restrict__ W1, const float* __restrict__ b1,
    const float* __restrict__ W2, const float* __restrict__ b2,
    float* __restrict__ out)
{
    // one wave per row; 4 independent waves per block; no LDS, no barriers
    const int lane = threadIdx.x & 63;
    const int wid  = threadIdx.x >> 6;
    const int row  = blockIdx.x * 4 + wid;

    const float* __restrict__ xr = x + (size_t)row * L_LEN;

    // conv weights -> uniform (scalar) regs
    const float* cws[4] = {cw0, cw1, cw2, cw3};
    const float* cbs[4] = {cb0, cb1, cb2, cb3};
    float w[4][9], bias[4];
#pragma unroll
    for (int s = 0; s < 4; ++s) {
        const int k = 3 + 2 * s;
        bias[s] = cbs[s][0];
#pragma unroll
        for (int t = 0; t < 9; ++t) w[s][t] = (t < k) ? cws[s][t] : 0.0f;
    }

    // lane t owns elements 12t .. 12t+11 ; lanes 60..63 idle (60*12 == 720)
    const bool active = lane < 60;
    float f[4][12];

    if (active) {
        // window: elements e0 .. e0+19, e0 = 12*lane - 4 (halo 4 each side)
        const int e0 = 12 * lane - 4;
        float xw[20];
#pragma unroll
        for (int q = 0; q < 5; ++q) {
            int e = e0 + 4 * q;
            e = (e < 0) ? 0 : ((e > L_LEN - 4) ? (L_LEN - 4) : e);   // stays 16B-aligned
            float4 v = *(const float4*)(xr + e);
            xw[4 * q + 0] = v.x; xw[4 * q + 1] = v.y;
            xw[4 * q + 2] = v.z; xw[4 * q + 3] = v.w;
        }
        if (lane == 0)  { xw[0] = 0.f; xw[1] = 0.f; xw[2] = 0.f; xw[3] = 0.f; }
        if (lane == 59) { xw[16] = 0.f; xw[17] = 0.f; xw[18] = 0.f; xw[19] = 0.f; }

#pragma unroll
        for (int s = 0; s < 4; ++s) {
            const int k = 3 + 2 * s;
            const int off = 3 - s;          // 4 - k/2
#pragma unroll
            for (int e = 0; e < 12; ++e) {
                float acc = bias[s];
#pragma unroll
                for (int u = 0; u < k; ++u)
                    acc = fmaf(w[s][u], xw[e + off + u], acc);
                f[s][e] = acc;
            }
        }
    } else {
#pragma unroll
        for (int s = 0; s < 4; ++s)
#pragma unroll
            for (int e = 0; e < 12; ++e) f[s][e] = -1e30f;  // exp -> 0
    }

    // Pin f in registers: opaque to the optimizer -> conv computed exactly once,
    // no rematerialization in the entropy / output passes. (48 VGPRs live.)
#pragma unroll
    for (int s = 0; s < 4; ++s)
#pragma unroll
        for (int e = 0; e < 12; ++e)
            asm volatile("" : "+v"(f[s][e]));

    // Entropy without max-shift (shift-invariant): S = sum e^f, T = sum f e^f,
    // entropy = log S - T/S.  f ~ O(few), exp is fp32-safe.
    float S[4] = {0.f, 0.f, 0.f, 0.f};
    float T[4] = {0.f, 0.f, 0.f, 0.f};
#pragma unroll
    for (int s = 0; s < 4; ++s) {
#pragma unroll
        for (int e = 0; e < 12; ++e) {
            float g  = f[s][e];
            float ev = __expf(g);           // exp(-1e30) == 0 for idle lanes
            S[s] += ev;
            T[s] = fmaf(g, ev, T[s]);       // finite * 0 == -0, safe
        }
    }
#pragma unroll
    for (int s = 0; s < 4; ++s) {
#pragma unroll
        for (int off = 32; off; off >>= 1) {
            S[s] += __shfl_xor(S[s], off);
            T[s] += __shfl_xor(T[s], off);
        }
    }
    float ent[4];
#pragma unroll
    for (int s = 0; s < 4; ++s) ent[s] = __logf(S[s]) - T[s] / S[s];

    // MLP: h = relu(ent @ W1 + b1), one hidden unit per lane (mod 32);
    // logits = h @ W2 + b2 via 32-lane shuffle reduce; softmax -> weights
    const int hidx = lane & 31;
    float h = b1[hidx];
#pragma unroll
    for (int s = 0; s < 4; ++s) h = fmaf(ent[s], W1[s * 32 + hidx], h);
    h = fmaxf(h, 0.0f);

    const float4 w2v = ((const float4*)W2)[hidx];
    float lg[4] = {h * w2v.x, h * w2v.y, h * w2v.z, h * w2v.w};
#pragma unroll
    for (int c = 0; c < 4; ++c) {
#pragma unroll
        for (int off = 16; off; off >>= 1)
            lg[c] += __shfl_xor(lg[c], off);
    }
    lg[0] += b2[0]; lg[1] += b2[1]; lg[2] += b2[2]; lg[3] += b2[3];

    float m = fmaxf(fmaxf(lg[0], lg[1]), fmaxf(lg[2], lg[3]));
    float e0w = __expf(lg[0] - m), e1w = __expf(lg[1] - m);
    float e2w = __expf(lg[2] - m), e3w = __expf(lg[3] - m);
    float inv = 1.0f / (e0w + e1w + e2w + e3w);
    const float w0 = e0w * inv, w1 = e1w * inv, w2 = e2w * inv, w3 = e3w * inv;

    // weighted sum from the pinned registers, float4 stores
    if (active) {
        float* __restrict__ orow = out + (size_t)row * L_LEN + 12 * lane;
#pragma unroll
        for (int q = 0; q < 3; ++q) {
            float4 v;
#pragma unroll
            for (int c = 0; c < 4; ++c) {
                const int e = 4 * q + c;
                float val = w0 * f[0][e];
                val = fmaf(w1, f[1][e], val);
                val = fmaf(w2, f[2][e], val);
                val = fmaf(w3, f[3][e], val);
                ((float*)&v)[c] = val;
            }
            *(float4*)(orow + 4 * q) = v;
        }
    }
}

extern "C" void kernel_launch(void* const* d_in, const int* in_sizes, int n_in,
                              void* d_out, int out_size, void* d_ws, size_t ws_size,
                              hipStream_t stream) {
    const float* xp  = (const float*)d_in[0];
    const float* cw0 = (const float*)d_in[1];
    const float* cb0 = (const float*)d_in[2];
    const float* cw1 = (const float*)d_in[3];
    const float* cb1 = (const float*)d_in[4];
    const float* cw2 = (const float*)d_in[5];
    const float* cb2 = (const float*)d_in[6];
    const float* cw3 = (const float*)d_in[7];
    const float* cb3 = (const float*)d_in[8];
    const float* W1  = (const float*)d_in[9];
    const float* b1  = (const float*)d_in[10];
    const float* W2  = (const float*)d_in[11];
    const float* b2  = (const float*)d_in[12];
    float* outp = (float*)d_out;

    trend_kernel<<<NROWS / 4, NT, 0, stream>>>(xp, cw0, cb0, cw1, cb1, cw2, cb2,
                                               cw3, cb3, W1, b1, W2, b2, outp);
}